// Round 8
// baseline (294.400 us; speedup 1.0000x reference)
//
#include <hip/hip_runtime.h>

typedef __bf16 bf16;
typedef __bf16 bf16x4 __attribute__((ext_vector_type(4)));
typedef __bf16 bf16x8 __attribute__((ext_vector_type(8)));
typedef float f32x4 __attribute__((ext_vector_type(4)));

#define NB 4
#define NS 2048
#define ND 1024
#define NH 16
#define HD 64

// 0.125 (1/sqrt(64)) * log2(e): folded into Q so attn uses raw exp2
#define QSCALE 0.18033688f

__device__ __forceinline__ void gload_lds16(const void* g, void* l) {
  __builtin_amdgcn_global_load_lds(
      (const __attribute__((address_space(1))) void*)g,
      (__attribute__((address_space(3))) void*)l, 16, 0, 0);
}

__device__ __forceinline__ float fast_exp2(float x) {
#if __has_builtin(__builtin_amdgcn_exp2f)
  return __builtin_amdgcn_exp2f(x);
#else
  return exp2f(x);
#endif
}

// ---------------- fp32 -> bf16 elementwise (x) ----------------
__global__ __launch_bounds__(256) void k_cvt(const float* __restrict__ src,
                                             bf16* __restrict__ dst) {
  size_t i = ((size_t)blockIdx.x * 256 + threadIdx.x) * 4;
  float4 v = *(const float4*)(src + i);
  bf16x4 o = {(__bf16)v.x, (__bf16)v.y, (__bf16)v.z, (__bf16)v.w};
  *(bf16x4*)(dst + i) = o;
}

// --- fp32 [1024][1024] -> bf16 transposed, all 4 weights in one launch ---
__global__ __launch_bounds__(256) void k_cvt_T4(const float* __restrict__ wq,
                                                const float* __restrict__ wk,
                                                const float* __restrict__ wv,
                                                const float* __restrict__ wo,
                                                bf16* __restrict__ wqkvT,
                                                bf16* __restrict__ woT) {
  int z = blockIdx.z;
  const float* src = z == 0 ? wq : z == 1 ? wk : z == 2 ? wv : wo;
  bf16* dst = z < 3 ? wqkvT + (size_t)z * 1048576 : woT;
  __shared__ float t[32][33];
  int tx = threadIdx.x, ty = threadIdx.y;
  int x = blockIdx.x * 32 + tx;
  int y = blockIdx.y * 32 + ty;
#pragma unroll
  for (int j = 0; j < 4; ++j)
    t[ty + j * 8][tx] = src[(size_t)(y + j * 8) * 1024 + x];
  __syncthreads();
  int x2 = blockIdx.y * 32 + tx;
  int y2 = blockIdx.x * 32 + ty;
#pragma unroll
  for (int j = 0; j < 4; ++j)
    dst[(size_t)(y2 + j * 8) * 1024 + x2] = (__bf16)t[tx][ty + j * 8];
}

// --- bf16 V natural [B,S,H,64] -> V^T [B,H,64,S] (coalesced both sides) ---
__global__ __launch_bounds__(256) void k_vT(const bf16* __restrict__ V,
                                            bf16* __restrict__ Vt) {
  __shared__ bf16 t[64][72];
  int tid = threadIdx.x;
  int bh = blockIdx.x >> 5, st = blockIdx.x & 31;
  int b = bh >> 4, h = bh & 15;
  const bf16* src = V + ((size_t)b * NS + st * 64) * ND + h * HD;
#pragma unroll
  for (int rep = 0; rep < 2; ++rep) {
    int idx = rep * 256 + tid;
    int r = idx >> 3, c8 = (idx & 7) * 8;
    *(bf16x8*)&t[r][c8] = *(const bf16x8*)(src + (size_t)r * ND + c8);
  }
  __syncthreads();
  bf16* dst = Vt + (size_t)bh * HD * NS + st * 64;
#pragma unroll
  for (int rep = 0; rep < 2; ++rep) {
    int idx = rep * 256 + tid;
    int d = idx >> 3, s8 = (idx & 7) * 8;
    bf16x8 v;
#pragma unroll
    for (int j = 0; j < 8; ++j) {  // j-rotation keeps LDS reads bank-balanced
      int jj = (j + tid) & 7;
      v[jj] = t[s8 + jj][d];
    }
    *(bf16x8*)(dst + (size_t)d * NS + s8) = v;
  }
}

// --- 256x128 8-wave bf16 GEMM mainloop, BK=32 double-buffered, 2 blk/CU ---
// R4's proven 2-phase discipline (one __syncthreads per K-tile, prefetch
// issued only after the barrier, own-drain implies prior tile landed) at
// HALF the K-step so the mainloop LDS is 48 KiB and whole-kernel LDS 72 KiB
// -> 2 blocks/CU (16 waves/CU): cross-block TLP covers the barrier drain
// (m97 mechanism; all 1-blk/CU schedule variants R4-R6 clustered together).
// Per barrier: 3 gload_lds + 8 ds_read_b128 + 16 MFMA per wave.
// 64 B LDS rows: bank half = row parity, so the granule XOR uses the
// row-parity-decorrelated sw=(row>>1)&3 (proven in attn's P tile); inverse
// applied at the global source, lane-linear LDS dest.
__device__ __forceinline__ void gemm256_mainloop(const bf16* __restrict__ A,
                                                 const bf16* __restrict__ BT,
                                                 int bm, int bn, bf16* As,
                                                 bf16* Bs, f32x4 acc[4][4]) {
  const int tid = threadIdx.x;
  const int w = tid >> 6, lane = tid & 63, quad = lane >> 4, l15 = lane & 15;
  const int wr = w >> 1, wc = w & 1;
  const int sw = (l15 >> 1) & 3;
  const int r4 = tid >> 2, g4 = tid & 3;  // 128 rows x 4 granules per issue
  const int gswz = (g4 ^ ((r4 >> 1) & 3)) * 8;
  const bf16* gA = A + (size_t)(bm * 256 + r4) * 1024 + gswz;
  const bf16* gB = BT + (size_t)(bn * 128 + r4) * 1024 + gswz;
  bf16* dA = As + w * 512;  // wave-uniform base; HW adds lane*16B
  bf16* dB = Bs + w * 512;
  int aoff[4], boff[4];
#pragma unroll
  for (int mi = 0; mi < 4; ++mi)
    aoff[mi] = (wr * 64 + mi * 16 + l15) * 32 + ((quad ^ sw) * 8);
#pragma unroll
  for (int ni = 0; ni < 4; ++ni)
    boff[ni] = (wc * 64 + ni * 16 + l15) * 32 + ((quad ^ sw) * 8);

  // stage K-tile kt into slot: A 256x32 (2 issues of 128 rows), B 128x32 (1)
  auto stage = [&](int kt, int slot) {
    const bf16* ga = gA + kt * 32;
    const bf16* gb = gB + kt * 32;
    gload_lds16(ga, dA + slot * 8192);
    gload_lds16(ga + (size_t)128 * 1024, dA + slot * 8192 + 4096);
    gload_lds16(gb, dB + slot * 4096);
  };

  stage(0, 0);
  for (int kt = 0; kt < 32; ++kt) {
    const int buf = kt & 1;
    __syncthreads();  // own kt-loads drained; all reads of buf^1 done
    if (kt + 1 < 32) stage(kt + 1, buf ^ 1);
    const bf16* a_ = As + buf * 8192;
    const bf16* b_ = Bs + buf * 4096;
    bf16x8 bv[4];
#pragma unroll
    for (int ni = 0; ni < 4; ++ni) bv[ni] = *(const bf16x8*)(b_ + boff[ni]);
#pragma unroll
    for (int mi = 0; mi < 4; ++mi) {
      bf16x8 av = *(const bf16x8*)(a_ + aoff[mi]);
#pragma unroll
      for (int ni = 0; ni < 4; ++ni)
        acc[mi][ni] = __builtin_amdgcn_mfma_f32_16x16x32_bf16(av, bv[ni],
                                                              acc[mi][ni], 0,
                                                              0, 0);
    }
  }
  __syncthreads();  // epilogue reuses the mainloop LDS
}

// QKV projection: Q (pre-scaled), K, V all stored natural [B,S,H,64]
// (= [8192][1024] row-major). grid (24, 32): 256-row x 128-col tiles.
__global__ __launch_bounds__(512, 4) void k_gemm_qkv(
    const bf16* __restrict__ A, const bf16* __restrict__ BT,
    const float* __restrict__ bq, const float* __restrict__ bk,
    const float* __restrict__ bv, bf16* __restrict__ Q, bf16* __restrict__ K,
    bf16* __restrict__ V) {
  __shared__ alignas(16) char smem[73728];  // mainloop 48K; epilogue 72K
  bf16* As = (bf16*)smem;            // 2 x 8192 elems
  bf16* Bs = (bf16*)(smem + 32768);  // 2 x 4096 elems
  f32x4 acc[4][4] = {};
  const int bm = blockIdx.y, bn = blockIdx.x;
  gemm256_mainloop(A, BT, bm, bn, As, Bs, acc);
  const int tid = threadIdx.x;
  const int w = tid >> 6, lane = tid & 63, quad = lane >> 4, l15 = lane & 15;
  const int wr = w >> 1, wc = w & 1;
  bf16* sEw = (bf16*)smem + w * 4608;  // per-wave [64][72]
  const int colbase = bn * 128 + wc * 64;  // multiple of 64 -> wave-uniform
  const int which = colbase >> 10;
  const int nnbase = colbase & 1023;
  const float* bias = which == 0 ? bq : which == 1 ? bk : bv;
  bf16* dst = which == 0 ? Q : which == 1 ? K : V;
  const float scl = which == 0 ? QSCALE : 1.f;
  const int rowbase = bm * 256 + wr * 64;
#pragma unroll
  for (int ni = 0; ni < 4; ++ni) {
    float bb = bias[nnbase + ni * 16 + l15];
#pragma unroll
    for (int mi = 0; mi < 4; ++mi)
#pragma unroll
      for (int r = 0; r < 4; ++r)
        sEw[(mi * 16 + quad * 4 + r) * 72 + ni * 16 + l15] =
            (__bf16)((acc[mi][ni][r] + bb) * scl);
  }
  // per-wave buffer: in-wave LDS ordering suffices, no barrier
  const int l8 = lane >> 3, g8 = (lane & 7) * 8;
#pragma unroll
  for (int i = 0; i < 8; ++i) {
    int row = i * 8 + l8;
    bf16x8 vv = *(const bf16x8*)(sEw + row * 72 + g8);
    *(bf16x8*)(dst + (size_t)(rowbase + row) * 1024 + nnbase + g8) = vv;
  }
}

// out projection: A=attn_out bf16 [8192][1024], BT=woT -> fp32 Y.
// grid (8, 32): 256-row x 128-col tiles; per-wave fp32 epilogue in 2 halves.
__global__ __launch_bounds__(512, 4) void k_gemm_out(
    const bf16* __restrict__ A, const bf16* __restrict__ BT,
    const float* __restrict__ bo, float* __restrict__ Y) {
  __shared__ alignas(16) char smem[73728];
  bf16* As = (bf16*)smem;
  bf16* Bs = (bf16*)(smem + 32768);
  f32x4 acc[4][4] = {};
  const int bm = blockIdx.y, bn = blockIdx.x;
  gemm256_mainloop(A, BT, bm, bn, As, Bs, acc);
  const int tid = threadIdx.x;
  const int w = tid >> 6, lane = tid & 63, quad = lane >> 4, l15 = lane & 15;
  const int wr = w >> 1, wc = w & 1;
  float* sEw = (float*)smem + w * 2176;  // per-wave [32][68] fp32
  const int colbase = bn * 128 + wc * 64;
  const int rowbase = bm * 256 + wr * 64;
  float bb[4];
#pragma unroll
  for (int ni = 0; ni < 4; ++ni) bb[ni] = bo[colbase + ni * 16 + l15];
  const int l4 = lane >> 4, c4 = (lane & 15) * 4;
#pragma unroll
  for (int h2 = 0; h2 < 2; ++h2) {
#pragma unroll
    for (int ml = 0; ml < 2; ++ml)
#pragma unroll
      for (int ni = 0; ni < 4; ++ni)
#pragma unroll
        for (int r = 0; r < 4; ++r)
          sEw[(ml * 16 + quad * 4 + r) * 68 + ni * 16 + l15] =
              acc[h2 * 2 + ml][ni][r] + bb[ni];
    // per-wave buffer; in-wave ordering (ds in-order) makes this safe
#pragma unroll
    for (int i = 0; i < 8; ++i) {
      int row = i * 4 + l4;
      float4 v = *(const float4*)(sEw + row * 68 + c4);
      *(float4*)(Y + (size_t)(rowbase + h2 * 32 + row) * 1024 + colbase + c4) =
          v;
    }
  }
}

// ---------------- flash attention v7 (proven 90.2 us) ----------------
// 1024 blocks, 4 waves x 32 q, 64-key chunks double-buffered, per-wave P tile
// [32 q][32 k] bf16 with row-parity-decorrelated granule swizzle
// sw = (l15>>1)&3. LDS 40960 B -> 4 blocks/CU, 16 waves/CU.
__global__ __launch_bounds__(256, 4) void k_attn(const bf16* __restrict__ Qg,
                                                 const bf16* __restrict__ Kg,
                                                 const bf16* __restrict__ VtG,
                                                 bf16* __restrict__ O) {
  __shared__ alignas(16) char smem[40960];
  bf16* sK = (bf16*)smem;              // 2 x 4096 elems
  bf16* sVt = (bf16*)(smem + 16384);   // 2 x 4096 elems
  const int tid = threadIdx.x;
  const int w = tid >> 6, lane = tid & 63, quad = lane >> 4, l15 = lane & 15;
  const int l7 = l15 & 7, l8 = lane >> 3;
  const int sw = (l15 >> 1) & 3;  // row-parity-decorrelated granule swizzle
  const int bh = blockIdx.x & 63;   // XCD-friendly: bh mod 8 fixed per bh
  const int qt = blockIdx.x >> 6;   // 0..15
  const int b = bh >> 4, h = bh & 15;
  const bf16* Qh = Qg + (size_t)b * NS * ND + h * HD;
  const bf16* Kh = Kg + (size_t)b * NS * ND + h * HD;
  const bf16* Vh = VtG + (size_t)bh * HD * NS;  // [64][2048]
  bf16* Pw = (bf16*)(smem + 32768) + w * 1024;  // per-wave [32][32] swizzled

  const int q0 = qt * 128 + w * 32;
  // Q B-fragments (pre-scaled at QKV epilogue), registers for whole kernel
  bf16x8 qb[2][2];
#pragma unroll
  for (int ni = 0; ni < 2; ++ni)
#pragma unroll
    for (int ks = 0; ks < 2; ++ks)
      qb[ni][ks] = *(const bf16x8*)(Qh + (size_t)(q0 + ni * 16 + l15) * ND +
                                    ks * 32 + quad * 8);

  // staging addresses (XOR-granule swizzle g^=row&7, lane-linear LDS dest)
  const int gsw = ((lane & 7) ^ l8) * 8;
  const bf16* gk = Kh + (size_t)(w * 8 + l8) * ND + gsw;
  const bf16* gv = Vh + (size_t)(w * 8 + l8) * NS + gsw;
  bf16* dk = sK + w * 512;
  bf16* dv = sVt + w * 512;

  f32x4 o_acc[4][2] = {};  // O^T: row d=mi*16+quad*4+r, col q=ni*16+l15
  float l_run[2] = {0.f, 0.f};  // lane-local partial denominators

  // chunk-invariant swizzled fragment offsets
  int offA[4][2];
#pragma unroll
  for (int mi = 0; mi < 4; ++mi)
#pragma unroll
    for (int ks = 0; ks < 2; ++ks)
      offA[mi][ks] = (mi * 16 + l15) * 64 + (((ks * 4 + quad) ^ l7) * 8);
  // P tile [32 q][32 k] bf16, 64 B rows, 4 granules of 16 B, XOR sw
  int offP[2], wbase[2], wg[2];
#pragma unroll
  for (int ni = 0; ni < 2; ++ni) {
    offP[ni] = (ni * 16 + l15) * 32 + ((quad ^ sw) * 8);
    wbase[ni] = (ni * 16 + l15) * 32 + (quad & 1) * 4;
  }
#pragma unroll
  for (int m2 = 0; m2 < 2; ++m2)
    wg[m2] = (((m2 * 2 + (quad >> 1)) ^ sw) * 8);

  // prologue: stage chunk 0 into buffer 0
  gload_lds16(gk, dk);
  gload_lds16(gk + 32 * ND, dk + 2048);
  gload_lds16(gv, dv);
  gload_lds16(gv + 32 * NS, dv + 2048);

  for (int it = 0; it < NS / 64; ++it) {
    const int buf = (it & 1) * 4096;
    __syncthreads();  // drains own chunk-it loads; all buf^1 reads done
    if (it + 1 < NS / 64) {
      const int nbuf = 4096 - buf;
      const bf16* gk1 = gk + (size_t)(it + 1) * 64 * ND;
      const bf16* gv1 = gv + (it + 1) * 64;
      gload_lds16(gk1, dk + nbuf);
      gload_lds16(gk1 + 32 * ND, dk + nbuf + 2048);
      gload_lds16(gv1, dv + nbuf);
      gload_lds16(gv1 + 32 * NS, dv + nbuf + 2048);
    }

#pragma unroll
    for (int hf = 0; hf < 2; ++hf) {  // 32-key half: keys hf*32..hf*32+31
      // S^T = K Q^T for mi = 2*hf + m2; exp2 + P-write immediately
#pragma unroll
      for (int m2 = 0; m2 < 2; ++m2) {
        const int mi = 2 * hf + m2;
        f32x4 s[2] = {};
#pragma unroll
        for (int ks = 0; ks < 2; ++ks) {
          bf16x8 ak = *(const bf16x8*)(sK + buf + offA[mi][ks]);
#pragma unroll
          for (int ni = 0; ni < 2; ++ni)
            s[ni] = __builtin_amdgcn_mfma_f32_16x16x32_bf16(ak, qb[ni][ks],
                                                            s[ni], 0, 0, 0);
        }
#pragma unroll
        for (int ni = 0; ni < 2; ++ni) {
#pragma unroll
          for (int r = 0; r < 4; ++r) {
            s[ni][r] = fast_exp2(s[ni][r]);
            l_run[ni] += s[ni][r];
          }
          bf16x4 p = {(__bf16)s[ni][0], (__bf16)s[ni][1], (__bf16)s[ni][2],
                      (__bf16)s[ni][3]};
          *(bf16x4*)(Pw + wbase[ni] + wg[m2]) = p;
        }
      }

      // O^T += V^T P^T for this 32-key half (ks = hf); per-wave P, no barrier
      bf16x8 pb[2];
#pragma unroll
      for (int ni = 0; ni < 2; ++ni)
        pb[ni] = *(const bf16x8*)(Pw + offP[ni]);
#pragma unroll
      for (int mi = 0; mi < 4; ++mi) {
        bf16x8 av = *(const bf16x8*)(sVt + buf + offA[mi][hf]);
#pragma unroll
        for (int ni = 0; ni < 2; ++ni)
          o_acc[mi][ni] = __builtin_amdgcn_mfma_f32_16x16x32_bf16(
              av, pb[ni], o_acc[mi][ni], 0, 0, 0);
      }
    }
  }

  // epilogue: finish denominator reduction, write attn_out [B,S,H*64] bf16
#pragma unroll
  for (int ni = 0; ni < 2; ++ni) {
    float l = l_run[ni];
    l += __shfl_xor(l, 16, 64);
    l += __shfl_xor(l, 32, 64);
    float inv = 1.f / l;
    int q = q0 + ni * 16 + l15;
    size_t orow = ((size_t)b * NS + q) * 1024 + h * 64;
#pragma unroll
    for (int mi = 0; mi < 4; ++mi) {
      bf16x4 ov = {
          (__bf16)(o_acc[mi][ni][0] * inv), (__bf16)(o_acc[mi][ni][1] * inv),
          (__bf16)(o_acc[mi][ni][2] * inv), (__bf16)(o_acc[mi][ni][3] * inv)};
      *(bf16x4*)(O + orow + mi * 16 + quad * 4) = ov;
    }
  }
}

// ---------------- LayerNorm (in-place on d_out) ----------------
__global__ __launch_bounds__(256) void k_ln(float* __restrict__ Y,
                                            const float* __restrict__ g,
                                            const float* __restrict__ bta) {
  int row = blockIdx.x, tid = threadIdx.x;
  float4 v = ((const float4*)(Y + (size_t)row * 1024))[tid];
  float sm = v.x + v.y + v.z + v.w;
  float sq = v.x * v.x + v.y * v.y + v.z * v.z + v.w * v.w;
#pragma unroll
  for (int off = 1; off < 64; off <<= 1) {
    sm += __shfl_xor(sm, off, 64);
    sq += __shfl_xor(sq, off, 64);
  }
  __shared__ float red[8];
  int w = tid >> 6, lane = tid & 63;
  if (lane == 0) {
    red[w] = sm;
    red[4 + w] = sq;
  }
  __syncthreads();
  sm = red[0] + red[1] + red[2] + red[3];
  sq = red[4] + red[5] + red[6] + red[7];
  float mu = sm * (1.f / 1024.f);
  float var = sq * (1.f / 1024.f) - mu * mu;
  float rstd = rsqrtf(var + 1e-12f);
  float4 g4 = ((const float4*)g)[tid];
  float4 b4 = ((const float4*)bta)[tid];
  float4 o;
  o.x = (v.x - mu) * rstd * g4.x + b4.x;
  o.y = (v.y - mu) * rstd * g4.y + b4.y;
  o.z = (v.z - mu) * rstd * g4.z + b4.z;
  o.w = (v.w - mu) * rstd * g4.w + b4.w;
  ((float4*)(Y + (size_t)row * 1024))[tid] = o;
}

extern "C" void kernel_launch(void* const* d_in, const int* in_sizes, int n_in,
                              void* d_out, int out_size, void* d_ws,
                              size_t ws_size, hipStream_t stream) {
  const float* x = (const float*)d_in[0];
  const float* wq = (const float*)d_in[1];
  const float* bq = (const float*)d_in[2];
  const float* wk = (const float*)d_in[3];
  const float* bk = (const float*)d_in[4];
  const float* wv = (const float*)d_in[5];
  const float* bv = (const float*)d_in[6];
  const float* wo = (const float*)d_in[7];
  const float* bo = (const float*)d_in[8];
  const float* ln_g = (const float*)d_in[9];
  const float* ln_b = (const float*)d_in[10];
  float* out = (float*)d_out;

  char* ws = (char*)d_ws;
  bf16* xb = (bf16*)ws;          ws += 16777216;   // [8192][1024]
  bf16* wqkvT = (bf16*)ws;       ws += 6291456;    // [3072][1024]
  bf16* woT = (bf16*)ws;         ws += 2097152;    // [1024][1024]
  bf16* Qh = (bf16*)ws;          ws += 16777216;   // [B,S,H,64] (pre-scaled)
  bf16* Kh = (bf16*)ws;          ws += 16777216;   // [B,S,H,64]
  bf16* Vh = (bf16*)ws;          ws += 16777216;   // [B,S,H,64]
  bf16* Vt = (bf16*)ws;          ws += 16777216;   // [B,H,64,S] (transposed)
  bf16* AOb = (bf16*)ws;         ws += 16777216;   // [8192][1024]

  k_cvt<<<8192, 256, 0, stream>>>(x, xb);
  dim3 tb(32, 8);
  k_cvt_T4<<<dim3(32, 32, 4), tb, 0, stream>>>(wq, wk, wv, wo, wqkvT, woT);

  k_gemm_qkv<<<dim3(24, 32), 512, 0, stream>>>(xb, wqkvT, bq, bk, bv, Qh, Kh,
                                               Vh);
  k_vT<<<NB * NH * 32, 256, 0, stream>>>(Vh, Vt);
  k_attn<<<NB * NH * (NS / 128), 256, 0, stream>>>(Qh, Kh, Vt, AOb);
  k_gemm_out<<<dim3(8, 32), 512, 0, stream>>>(AOb, woT, bo, out);
  k_ln<<<8192, 256, 0, stream>>>(out, ln_g, ln_b);
}

// Round 9
// 291.515 us; speedup vs baseline: 1.0099x; 1.0099x over previous
//
#include <hip/hip_runtime.h>

typedef __bf16 bf16;
typedef __bf16 bf16x4 __attribute__((ext_vector_type(4)));
typedef __bf16 bf16x8 __attribute__((ext_vector_type(8)));
typedef float f32x4 __attribute__((ext_vector_type(4)));

#define NB 4
#define NS 2048
#define ND 1024
#define NH 16
#define HD 64

// 0.125 (1/sqrt(64)) * log2(e): folded into Q so attn uses raw exp2
#define QSCALE 0.18033688f

__device__ __forceinline__ void gload_lds16(const void* g, void* l) {
  __builtin_amdgcn_global_load_lds(
      (const __attribute__((address_space(1))) void*)g,
      (__attribute__((address_space(3))) void*)l, 16, 0, 0);
}

__device__ __forceinline__ float fast_exp2(float x) {
#if __has_builtin(__builtin_amdgcn_exp2f)
  return __builtin_amdgcn_exp2f(x);
#else
  return exp2f(x);
#endif
}

// ---------------- fp32 -> bf16 elementwise (x) ----------------
__global__ __launch_bounds__(256) void k_cvt(const float* __restrict__ src,
                                             bf16* __restrict__ dst) {
  size_t i = ((size_t)blockIdx.x * 256 + threadIdx.x) * 4;
  float4 v = *(const float4*)(src + i);
  bf16x4 o = {(__bf16)v.x, (__bf16)v.y, (__bf16)v.z, (__bf16)v.w};
  *(bf16x4*)(dst + i) = o;
}

// --- fp32 [1024][1024] -> bf16 transposed, all 4 weights in one launch ---
__global__ __launch_bounds__(256) void k_cvt_T4(const float* __restrict__ wq,
                                                const float* __restrict__ wk,
                                                const float* __restrict__ wv,
                                                const float* __restrict__ wo,
                                                bf16* __restrict__ wqkvT,
                                                bf16* __restrict__ woT) {
  int z = blockIdx.z;
  const float* src = z == 0 ? wq : z == 1 ? wk : z == 2 ? wv : wo;
  bf16* dst = z < 3 ? wqkvT + (size_t)z * 1048576 : woT;
  __shared__ float t[32][33];
  int tx = threadIdx.x, ty = threadIdx.y;
  int x = blockIdx.x * 32 + tx;
  int y = blockIdx.y * 32 + ty;
#pragma unroll
  for (int j = 0; j < 4; ++j)
    t[ty + j * 8][tx] = src[(size_t)(y + j * 8) * 1024 + x];
  __syncthreads();
  int x2 = blockIdx.y * 32 + tx;
  int y2 = blockIdx.x * 32 + ty;
#pragma unroll
  for (int j = 0; j < 4; ++j)
    dst[(size_t)(y2 + j * 8) * 1024 + x2] = (__bf16)t[tx][ty + j * 8];
}

// --- bf16 V natural [B,S,H,64] -> V^T [B,H,64,S] (coalesced both sides) ---
__global__ __launch_bounds__(256) void k_vT(const bf16* __restrict__ V,
                                            bf16* __restrict__ Vt) {
  __shared__ bf16 t[64][72];
  int tid = threadIdx.x;
  int bh = blockIdx.x >> 5, st = blockIdx.x & 31;
  int b = bh >> 4, h = bh & 15;
  const bf16* src = V + ((size_t)b * NS + st * 64) * ND + h * HD;
#pragma unroll
  for (int rep = 0; rep < 2; ++rep) {
    int idx = rep * 256 + tid;
    int r = idx >> 3, c8 = (idx & 7) * 8;
    *(bf16x8*)&t[r][c8] = *(const bf16x8*)(src + (size_t)r * ND + c8);
  }
  __syncthreads();
  bf16* dst = Vt + (size_t)bh * HD * NS + st * 64;
#pragma unroll
  for (int rep = 0; rep < 2; ++rep) {
    int idx = rep * 256 + tid;
    int d = idx >> 3, s8 = (idx & 7) * 8;
    bf16x8 v;
#pragma unroll
    for (int j = 0; j < 8; ++j) {  // j-rotation keeps LDS reads bank-balanced
      int jj = (j + tid) & 7;
      v[jj] = t[s8 + jj][d];
    }
    *(bf16x8*)(dst + (size_t)d * NS + s8) = v;
  }
}

// --- 256x128 8-wave bf16 GEMM mainloop, plain 2-phase (R4, best measured) --
// 8 waves as 4(M)x2(N); per-wave 64x64 output = acc[4][4]. LDS: As 2x[256][64],
// Bs 2x[128][64] bf16 = 96 KiB double-buffered. Staging and swizzle as the
// proven attn kernel: gload_lds16 lane-linear LDS dest, XOR-granule
// (g ^= row&7) applied to the GLOBAL source; ds_read_b128 frags read with the
// same XOR -> 2-way bank aliasing (free). One __syncthreads() per K-tile:
// prefetch for kt+1 issued only after the barrier; own vmcnt(0) drain inside
// __syncthreads() guarantees tile kt landed. 32 MFMA/wave per barrier.
__device__ __forceinline__ void gemm256_mainloop(const bf16* __restrict__ A,
                                                 const bf16* __restrict__ BT,
                                                 int bm, int bn, bf16* As,
                                                 bf16* Bs, f32x4 acc[4][4]) {
  const int tid = threadIdx.x;
  const int w = tid >> 6, lane = tid & 63, quad = lane >> 4, l15 = lane & 15;
  const int l7 = l15 & 7, l8 = lane >> 3;
  const int wr = w >> 1, wc = w & 1;
  const int gsw = ((lane & 7) ^ l8) * 8;
  const bf16* gaw = A + (size_t)(bm * 256 + w * 8 + l8) * 1024 + gsw;
  const bf16* gbw = BT + (size_t)(bn * 128 + w * 8 + l8) * 1024 + gsw;
  bf16* daw = As + w * 512;  // wave-uniform base; HW adds lane*16B
  bf16* dbw = Bs + w * 512;
  int aoff[4][2], boff[4][2];
#pragma unroll
  for (int mi = 0; mi < 4; ++mi)
#pragma unroll
    for (int ks = 0; ks < 2; ++ks)
      aoff[mi][ks] =
          (wr * 64 + mi * 16 + l15) * 64 + (((ks * 4 + quad) ^ l7) * 8);
#pragma unroll
  for (int ni = 0; ni < 4; ++ni)
#pragma unroll
    for (int ks = 0; ks < 2; ++ks)
      boff[ni][ks] =
          (wc * 64 + ni * 16 + l15) * 64 + (((ks * 4 + quad) ^ l7) * 8);

  // prologue: stage K-tile 0 into buffer 0
#pragma unroll
  for (int ri = 0; ri < 4; ++ri)
    gload_lds16(gaw + (size_t)(ri * 64) * 1024, daw + ri * 4096);
#pragma unroll
  for (int ri = 0; ri < 2; ++ri)
    gload_lds16(gbw + (size_t)(ri * 64) * 1024, dbw + ri * 4096);

  for (int kt = 0; kt < 16; ++kt) {
    const int buf = kt & 1;
    __syncthreads();  // own kt-loads drained; all reads of buf^1 done
    if (kt + 1 < 16) {
      const bf16* ga = gaw + (kt + 1) * 64;
      const bf16* gb = gbw + (kt + 1) * 64;
      bf16* da = daw + (buf ^ 1) * 16384;
      bf16* db = dbw + (buf ^ 1) * 8192;
#pragma unroll
      for (int ri = 0; ri < 4; ++ri)
        gload_lds16(ga + (size_t)(ri * 64) * 1024, da + ri * 4096);
#pragma unroll
      for (int ri = 0; ri < 2; ++ri)
        gload_lds16(gb + (size_t)(ri * 64) * 1024, db + ri * 4096);
    }
    const bf16* a_ = As + buf * 16384;
    const bf16* b_ = Bs + buf * 8192;
#pragma unroll
    for (int ks = 0; ks < 2; ++ks) {
      bf16x8 av[4], bv[4];
#pragma unroll
      for (int i = 0; i < 4; ++i)
        av[i] = *(const bf16x8*)(a_ + aoff[i][ks]);
#pragma unroll
      for (int i = 0; i < 4; ++i)
        bv[i] = *(const bf16x8*)(b_ + boff[i][ks]);
#pragma unroll
      for (int mi = 0; mi < 4; ++mi)
#pragma unroll
        for (int ni = 0; ni < 4; ++ni)
          acc[mi][ni] = __builtin_amdgcn_mfma_f32_16x16x32_bf16(
              av[mi], bv[ni], acc[mi][ni], 0, 0, 0);
    }
  }
  __syncthreads();  // epilogue reuses the mainloop LDS
}

// QKV projection: Q (pre-scaled), K, V all stored natural [B,S,H,64]
// (= [8192][1024] row-major). grid (24, 32): 256-row x 128-col tiles.
__global__ __launch_bounds__(512, 2) void k_gemm_qkv(
    const bf16* __restrict__ A, const bf16* __restrict__ BT,
    const float* __restrict__ bq, const float* __restrict__ bk,
    const float* __restrict__ bv, bf16* __restrict__ Q, bf16* __restrict__ K,
    bf16* __restrict__ V) {
  __shared__ alignas(16) char smem[98304];
  bf16* As = (bf16*)smem;            // 2 x 16384 elems
  bf16* Bs = (bf16*)(smem + 65536);  // 2 x 8192 elems
  f32x4 acc[4][4] = {};
  const int bm = blockIdx.y, bn = blockIdx.x;
  gemm256_mainloop(A, BT, bm, bn, As, Bs, acc);
  const int tid = threadIdx.x;
  const int w = tid >> 6, lane = tid & 63, quad = lane >> 4, l15 = lane & 15;
  const int wr = w >> 1, wc = w & 1;
  bf16* sEw = (bf16*)smem + w * 4608;  // per-wave [64][72]
  const int colbase = bn * 128 + wc * 64;  // multiple of 64 -> wave-uniform
  const int which = colbase >> 10;
  const int nnbase = colbase & 1023;
  const float* bias = which == 0 ? bq : which == 1 ? bk : bv;
  bf16* dst = which == 0 ? Q : which == 1 ? K : V;
  const float scl = which == 0 ? QSCALE : 1.f;
  const int rowbase = bm * 256 + wr * 64;
#pragma unroll
  for (int ni = 0; ni < 4; ++ni) {
    float bb = bias[nnbase + ni * 16 + l15];
#pragma unroll
    for (int mi = 0; mi < 4; ++mi)
#pragma unroll
      for (int r = 0; r < 4; ++r)
        sEw[(mi * 16 + quad * 4 + r) * 72 + ni * 16 + l15] =
            (__bf16)((acc[mi][ni][r] + bb) * scl);
  }
  // per-wave buffer: in-wave LDS ordering suffices, no barrier
  const int l8 = lane >> 3, g8 = (lane & 7) * 8;
#pragma unroll
  for (int i = 0; i < 8; ++i) {
    int row = i * 8 + l8;
    bf16x8 vv = *(const bf16x8*)(sEw + row * 72 + g8);
    *(bf16x8*)(dst + (size_t)(rowbase + row) * 1024 + nnbase + g8) = vv;
  }
}

// out projection: A=attn_out bf16 [8192][1024], BT=woT -> BF16 Yb (LN input).
// grid (8, 32): 256-row x 128-col tiles; qkv-style bf16 [64][72] epilogue.
// bf16-Y halves the Y write + LN read traffic (32 MB saved); R7 verified
// absmax unchanged (0.03125) with this exact rounding point.
__global__ __launch_bounds__(512, 2) void k_gemm_out(
    const bf16* __restrict__ A, const bf16* __restrict__ BT,
    const float* __restrict__ bo, bf16* __restrict__ Yb) {
  __shared__ alignas(16) char smem[98304];
  bf16* As = (bf16*)smem;
  bf16* Bs = (bf16*)(smem + 65536);
  f32x4 acc[4][4] = {};
  const int bm = blockIdx.y, bn = blockIdx.x;
  gemm256_mainloop(A, BT, bm, bn, As, Bs, acc);
  const int tid = threadIdx.x;
  const int w = tid >> 6, lane = tid & 63, quad = lane >> 4, l15 = lane & 15;
  const int wr = w >> 1, wc = w & 1;
  bf16* sEw = (bf16*)smem + w * 4608;  // per-wave [64][72]
  const int colbase = bn * 128 + wc * 64;
  const int rowbase = bm * 256 + wr * 64;
#pragma unroll
  for (int ni = 0; ni < 4; ++ni) {
    float bb = bo[colbase + ni * 16 + l15];
#pragma unroll
    for (int mi = 0; mi < 4; ++mi)
#pragma unroll
      for (int r = 0; r < 4; ++r)
        sEw[(mi * 16 + quad * 4 + r) * 72 + ni * 16 + l15] =
            (__bf16)(acc[mi][ni][r] + bb);
  }
  // per-wave buffer; in-wave ordering (ds in-order) makes this safe
  const int l8 = lane >> 3, g8 = (lane & 7) * 8;
#pragma unroll
  for (int i = 0; i < 8; ++i) {
    int row = i * 8 + l8;
    bf16x8 vv = *(const bf16x8*)(sEw + row * 72 + g8);
    *(bf16x8*)(Yb + (size_t)(rowbase + row) * 1024 + colbase + g8) = vv;
  }
}

// ---------------- flash attention v7 (proven 90.2 us) ----------------
// 1024 blocks, 4 waves x 32 q, 64-key chunks double-buffered, per-wave P tile
// [32 q][32 k] bf16 with row-parity-decorrelated granule swizzle
// sw = (l15>>1)&3. LDS 40960 B -> 4 blocks/CU, 16 waves/CU.
__global__ __launch_bounds__(256, 4) void k_attn(const bf16* __restrict__ Qg,
                                                 const bf16* __restrict__ Kg,
                                                 const bf16* __restrict__ VtG,
                                                 bf16* __restrict__ O) {
  __shared__ alignas(16) char smem[40960];
  bf16* sK = (bf16*)smem;              // 2 x 4096 elems
  bf16* sVt = (bf16*)(smem + 16384);   // 2 x 4096 elems
  const int tid = threadIdx.x;
  const int w = tid >> 6, lane = tid & 63, quad = lane >> 4, l15 = lane & 15;
  const int l7 = l15 & 7, l8 = lane >> 3;
  const int sw = (l15 >> 1) & 3;  // row-parity-decorrelated granule swizzle
  const int bh = blockIdx.x & 63;   // XCD-friendly: bh mod 8 fixed per bh
  const int qt = blockIdx.x >> 6;   // 0..15
  const int b = bh >> 4, h = bh & 15;
  const bf16* Qh = Qg + (size_t)b * NS * ND + h * HD;
  const bf16* Kh = Kg + (size_t)b * NS * ND + h * HD;
  const bf16* Vh = VtG + (size_t)bh * HD * NS;  // [64][2048]
  bf16* Pw = (bf16*)(smem + 32768) + w * 1024;  // per-wave [32][32] swizzled

  const int q0 = qt * 128 + w * 32;
  // Q B-fragments (pre-scaled at QKV epilogue), registers for whole kernel
  bf16x8 qb[2][2];
#pragma unroll
  for (int ni = 0; ni < 2; ++ni)
#pragma unroll
    for (int ks = 0; ks < 2; ++ks)
      qb[ni][ks] = *(const bf16x8*)(Qh + (size_t)(q0 + ni * 16 + l15) * ND +
                                    ks * 32 + quad * 8);

  // staging addresses (XOR-granule swizzle g^=row&7, lane-linear LDS dest)
  const int gsw = ((lane & 7) ^ l8) * 8;
  const bf16* gk = Kh + (size_t)(w * 8 + l8) * ND + gsw;
  const bf16* gv = Vh + (size_t)(w * 8 + l8) * NS + gsw;
  bf16* dk = sK + w * 512;
  bf16* dv = sVt + w * 512;

  f32x4 o_acc[4][2] = {};  // O^T: row d=mi*16+quad*4+r, col q=ni*16+l15
  float l_run[2] = {0.f, 0.f};  // lane-local partial denominators

  // chunk-invariant swizzled fragment offsets
  int offA[4][2];
#pragma unroll
  for (int mi = 0; mi < 4; ++mi)
#pragma unroll
    for (int ks = 0; ks < 2; ++ks)
      offA[mi][ks] = (mi * 16 + l15) * 64 + (((ks * 4 + quad) ^ l7) * 8);
  // P tile [32 q][32 k] bf16, 64 B rows, 4 granules of 16 B, XOR sw
  int offP[2], wbase[2], wg[2];
#pragma unroll
  for (int ni = 0; ni < 2; ++ni) {
    offP[ni] = (ni * 16 + l15) * 32 + ((quad ^ sw) * 8);
    wbase[ni] = (ni * 16 + l15) * 32 + (quad & 1) * 4;
  }
#pragma unroll
  for (int m2 = 0; m2 < 2; ++m2)
    wg[m2] = (((m2 * 2 + (quad >> 1)) ^ sw) * 8);

  // prologue: stage chunk 0 into buffer 0
  gload_lds16(gk, dk);
  gload_lds16(gk + 32 * ND, dk + 2048);
  gload_lds16(gv, dv);
  gload_lds16(gv + 32 * NS, dv + 2048);

  for (int it = 0; it < NS / 64; ++it) {
    const int buf = (it & 1) * 4096;
    __syncthreads();  // drains own chunk-it loads; all buf^1 reads done
    if (it + 1 < NS / 64) {
      const int nbuf = 4096 - buf;
      const bf16* gk1 = gk + (size_t)(it + 1) * 64 * ND;
      const bf16* gv1 = gv + (it + 1) * 64;
      gload_lds16(gk1, dk + nbuf);
      gload_lds16(gk1 + 32 * ND, dk + nbuf + 2048);
      gload_lds16(gv1, dv + nbuf);
      gload_lds16(gv1 + 32 * NS, dv + nbuf + 2048);
    }

#pragma unroll
    for (int hf = 0; hf < 2; ++hf) {  // 32-key half: keys hf*32..hf*32+31
      // S^T = K Q^T for mi = 2*hf + m2; exp2 + P-write immediately
#pragma unroll
      for (int m2 = 0; m2 < 2; ++m2) {
        const int mi = 2 * hf + m2;
        f32x4 s[2] = {};
#pragma unroll
        for (int ks = 0; ks < 2; ++ks) {
          bf16x8 ak = *(const bf16x8*)(sK + buf + offA[mi][ks]);
#pragma unroll
          for (int ni = 0; ni < 2; ++ni)
            s[ni] = __builtin_amdgcn_mfma_f32_16x16x32_bf16(ak, qb[ni][ks],
                                                            s[ni], 0, 0, 0);
        }
#pragma unroll
        for (int ni = 0; ni < 2; ++ni) {
#pragma unroll
          for (int r = 0; r < 4; ++r) {
            s[ni][r] = fast_exp2(s[ni][r]);
            l_run[ni] += s[ni][r];
          }
          bf16x4 p = {(__bf16)s[ni][0], (__bf16)s[ni][1], (__bf16)s[ni][2],
                      (__bf16)s[ni][3]};
          *(bf16x4*)(Pw + wbase[ni] + wg[m2]) = p;
        }
      }

      // O^T += V^T P^T for this 32-key half (ks = hf); per-wave P, no barrier
      bf16x8 pb[2];
#pragma unroll
      for (int ni = 0; ni < 2; ++ni)
        pb[ni] = *(const bf16x8*)(Pw + offP[ni]);
#pragma unroll
      for (int mi = 0; mi < 4; ++mi) {
        bf16x8 av = *(const bf16x8*)(sVt + buf + offA[mi][hf]);
#pragma unroll
        for (int ni = 0; ni < 2; ++ni)
          o_acc[mi][ni] = __builtin_amdgcn_mfma_f32_16x16x32_bf16(
              av, pb[ni], o_acc[mi][ni], 0, 0, 0);
      }
    }
  }

  // epilogue: finish denominator reduction, write attn_out [B,S,H*64] bf16
#pragma unroll
  for (int ni = 0; ni < 2; ++ni) {
    float l = l_run[ni];
    l += __shfl_xor(l, 16, 64);
    l += __shfl_xor(l, 32, 64);
    float inv = 1.f / l;
    int q = q0 + ni * 16 + l15;
    size_t orow = ((size_t)b * NS + q) * 1024 + h * 64;
#pragma unroll
    for (int mi = 0; mi < 4; ++mi) {
      bf16x4 ov = {
          (__bf16)(o_acc[mi][ni][0] * inv), (__bf16)(o_acc[mi][ni][1] * inv),
          (__bf16)(o_acc[mi][ni][2] * inv), (__bf16)(o_acc[mi][ni][3] * inv)};
      *(bf16x4*)(O + orow + mi * 16 + quad * 4) = ov;
    }
  }
}

// ------------- LayerNorm: bf16 Yb in -> fp32 out (saves 32MB traffic) ------
__global__ __launch_bounds__(256) void k_ln(const bf16* __restrict__ Yb,
                                            const float* __restrict__ g,
                                            const float* __restrict__ bta,
                                            float* __restrict__ out) {
  int row = blockIdx.x, tid = threadIdx.x;
  bf16x4 vb = *(const bf16x4*)(Yb + (size_t)row * 1024 + tid * 4);
  float4 v = {(float)vb[0], (float)vb[1], (float)vb[2], (float)vb[3]};
  float sm = v.x + v.y + v.z + v.w;
  float sq = v.x * v.x + v.y * v.y + v.z * v.z + v.w * v.w;
#pragma unroll
  for (int off = 1; off < 64; off <<= 1) {
    sm += __shfl_xor(sm, off, 64);
    sq += __shfl_xor(sq, off, 64);
  }
  __shared__ float red[8];
  int w = tid >> 6, lane = tid & 63;
  if (lane == 0) {
    red[w] = sm;
    red[4 + w] = sq;
  }
  __syncthreads();
  sm = red[0] + red[1] + red[2] + red[3];
  sq = red[4] + red[5] + red[6] + red[7];
  float mu = sm * (1.f / 1024.f);
  float var = sq * (1.f / 1024.f) - mu * mu;
  float rstd = rsqrtf(var + 1e-12f);
  float4 g4 = ((const float4*)g)[tid];
  float4 b4 = ((const float4*)bta)[tid];
  float4 o;
  o.x = (v.x - mu) * rstd * g4.x + b4.x;
  o.y = (v.y - mu) * rstd * g4.y + b4.y;
  o.z = (v.z - mu) * rstd * g4.z + b4.z;
  o.w = (v.w - mu) * rstd * g4.w + b4.w;
  ((float4*)(out + (size_t)row * 1024))[tid] = o;
}

extern "C" void kernel_launch(void* const* d_in, const int* in_sizes, int n_in,
                              void* d_out, int out_size, void* d_ws,
                              size_t ws_size, hipStream_t stream) {
  const float* x = (const float*)d_in[0];
  const float* wq = (const float*)d_in[1];
  const float* bq = (const float*)d_in[2];
  const float* wk = (const float*)d_in[3];
  const float* bk = (const float*)d_in[4];
  const float* wv = (const float*)d_in[5];
  const float* bv = (const float*)d_in[6];
  const float* wo = (const float*)d_in[7];
  const float* bo = (const float*)d_in[8];
  const float* ln_g = (const float*)d_in[9];
  const float* ln_b = (const float*)d_in[10];
  float* out = (float*)d_out;

  char* ws = (char*)d_ws;
  bf16* xb = (bf16*)ws;          ws += 16777216;   // [8192][1024]
  bf16* wqkvT = (bf16*)ws;       ws += 6291456;    // [3072][1024]
  bf16* woT = (bf16*)ws;         ws += 2097152;    // [1024][1024]
  bf16* Qh = (bf16*)ws;          ws += 16777216;   // [B,S,H,64] (pre-scaled)
  bf16* Kh = (bf16*)ws;          ws += 16777216;   // [B,S,H,64]
  bf16* Vh = (bf16*)ws;          ws += 16777216;   // [B,S,H,64]
  bf16* Vt = (bf16*)ws;          ws += 16777216;   // [B,H,64,S] (transposed)
  bf16* AOb = (bf16*)ws;         ws += 16777216;   // [8192][1024]
  bf16* Yb = (bf16*)ws;          ws += 16777216;   // [8192][1024] (LN input)

  k_cvt<<<8192, 256, 0, stream>>>(x, xb);
  dim3 tb(32, 8);
  k_cvt_T4<<<dim3(32, 32, 4), tb, 0, stream>>>(wq, wk, wv, wo, wqkvT, woT);

  k_gemm_qkv<<<dim3(24, 32), 512, 0, stream>>>(xb, wqkvT, bq, bk, bv, Qh, Kh,
                                               Vh);
  k_vT<<<NB * NH * 32, 256, 0, stream>>>(Vh, Vt);
  k_attn<<<NB * NH * (NS / 128), 256, 0, stream>>>(Qh, Kh, Vt, AOb);
  k_gemm_out<<<dim3(8, 32), 512, 0, stream>>>(AOb, woT, bo, Yb);
  k_ln<<<8192, 256, 0, stream>>>(Yb, ln_g, ln_b, out);
}

// Round 10
// 286.965 us; speedup vs baseline: 1.0259x; 1.0159x over previous
//
#include <hip/hip_runtime.h>

typedef __bf16 bf16;
typedef __bf16 bf16x4 __attribute__((ext_vector_type(4)));
typedef __bf16 bf16x8 __attribute__((ext_vector_type(8)));
typedef float f32x4 __attribute__((ext_vector_type(4)));

#define NB 4
#define NS 2048
#define ND 1024
#define NH 16
#define HD 64

// 0.125 (1/sqrt(64)) * log2(e): folded into Q so attn uses raw exp2
#define QSCALE 0.18033688f

__device__ __forceinline__ void gload_lds16(const void* g, void* l) {
  __builtin_amdgcn_global_load_lds(
      (const __attribute__((address_space(1))) void*)g,
      (__attribute__((address_space(3))) void*)l, 16, 0, 0);
}

__device__ __forceinline__ float fast_exp2(float x) {
#if __has_builtin(__builtin_amdgcn_exp2f)
  return __builtin_amdgcn_exp2f(x);
#else
  return exp2f(x);
#endif
}

// ---- merged prep: fp32->bf16 cvt of x  +  4x weight transpose-cvt ----
// One launch instead of two (k_cvt + k_cvt_T4): identical per-block work,
// whole-block branch on blockIdx (no divergence). Blocks [0,8192): x cvt;
// blocks [8192,12288): weight tiles, z = (bid-8192)>>10 selects the matrix.
__global__ __launch_bounds__(256) void k_prep(
    const float* __restrict__ x, bf16* __restrict__ xb,
    const float* __restrict__ wq, const float* __restrict__ wk,
    const float* __restrict__ wv, const float* __restrict__ wo,
    bf16* __restrict__ wqkvT, bf16* __restrict__ woT) {
  __shared__ float t[32][33];
  const int bid = blockIdx.x, tid = threadIdx.x;
  if (bid < 8192) {
    size_t i = ((size_t)bid * 256 + tid) * 4;
    float4 v = *(const float4*)(x + i);
    bf16x4 o = {(__bf16)v.x, (__bf16)v.y, (__bf16)v.z, (__bf16)v.w};
    *(bf16x4*)(xb + i) = o;
    return;
  }
  const int r = bid - 8192;
  const int z = r >> 10;               // 0..3: wq, wk, wv, wo
  const int bx = r & 31, by = (r >> 5) & 31;
  const float* src = z == 0 ? wq : z == 1 ? wk : z == 2 ? wv : wo;
  bf16* dst = z < 3 ? wqkvT + (size_t)z * 1048576 : woT;
  const int tx = tid & 31, ty = tid >> 5;  // (32, 8) layout
  const int xx = bx * 32 + tx;
  const int yy = by * 32 + ty;
#pragma unroll
  for (int j = 0; j < 4; ++j)
    t[ty + j * 8][tx] = src[(size_t)(yy + j * 8) * 1024 + xx];
  __syncthreads();
  const int x2 = by * 32 + tx;
  const int y2 = bx * 32 + ty;
#pragma unroll
  for (int j = 0; j < 4; ++j)
    dst[(size_t)(y2 + j * 8) * 1024 + x2] = (__bf16)t[tx][ty + j * 8];
}

// --- bf16 V natural [B,S,H,64] -> V^T [B,H,64,S] (coalesced both sides) ---
__global__ __launch_bounds__(256) void k_vT(const bf16* __restrict__ V,
                                            bf16* __restrict__ Vt) {
  __shared__ bf16 t[64][72];
  int tid = threadIdx.x;
  int bh = blockIdx.x >> 5, st = blockIdx.x & 31;
  int b = bh >> 4, h = bh & 15;
  const bf16* src = V + ((size_t)b * NS + st * 64) * ND + h * HD;
#pragma unroll
  for (int rep = 0; rep < 2; ++rep) {
    int idx = rep * 256 + tid;
    int r = idx >> 3, c8 = (idx & 7) * 8;
    *(bf16x8*)&t[r][c8] = *(const bf16x8*)(src + (size_t)r * ND + c8);
  }
  __syncthreads();
  bf16* dst = Vt + (size_t)bh * HD * NS + st * 64;
#pragma unroll
  for (int rep = 0; rep < 2; ++rep) {
    int idx = rep * 256 + tid;
    int d = idx >> 3, s8 = (idx & 7) * 8;
    bf16x8 v;
#pragma unroll
    for (int j = 0; j < 8; ++j) {  // j-rotation keeps LDS reads bank-balanced
      int jj = (j + tid) & 7;
      v[jj] = t[s8 + jj][d];
    }
    *(bf16x8*)(dst + (size_t)d * NS + s8) = v;
  }
}

// --- 256x128 8-wave bf16 GEMM mainloop, plain 2-phase (R4, best measured) --
// 8 waves as 4(M)x2(N); per-wave 64x64 output = acc[4][4]. LDS: As 2x[256][64],
// Bs 2x[128][64] bf16 = 96 KiB double-buffered. Staging and swizzle as the
// proven attn kernel: gload_lds16 lane-linear LDS dest, XOR-granule
// (g ^= row&7) applied to the GLOBAL source; ds_read_b128 frags read with the
// same XOR -> 2-way bank aliasing (free). One __syncthreads() per K-tile:
// prefetch for kt+1 issued only after the barrier; own vmcnt(0) drain inside
// __syncthreads() guarantees tile kt landed. 32 MFMA/wave per barrier.
__device__ __forceinline__ void gemm256_mainloop(const bf16* __restrict__ A,
                                                 const bf16* __restrict__ BT,
                                                 int bm, int bn, bf16* As,
                                                 bf16* Bs, f32x4 acc[4][4]) {
  const int tid = threadIdx.x;
  const int w = tid >> 6, lane = tid & 63, quad = lane >> 4, l15 = lane & 15;
  const int l7 = l15 & 7, l8 = lane >> 3;
  const int wr = w >> 1, wc = w & 1;
  const int gsw = ((lane & 7) ^ l8) * 8;
  const bf16* gaw = A + (size_t)(bm * 256 + w * 8 + l8) * 1024 + gsw;
  const bf16* gbw = BT + (size_t)(bn * 128 + w * 8 + l8) * 1024 + gsw;
  bf16* daw = As + w * 512;  // wave-uniform base; HW adds lane*16B
  bf16* dbw = Bs + w * 512;
  int aoff[4][2], boff[4][2];
#pragma unroll
  for (int mi = 0; mi < 4; ++mi)
#pragma unroll
    for (int ks = 0; ks < 2; ++ks)
      aoff[mi][ks] =
          (wr * 64 + mi * 16 + l15) * 64 + (((ks * 4 + quad) ^ l7) * 8);
#pragma unroll
  for (int ni = 0; ni < 4; ++ni)
#pragma unroll
    for (int ks = 0; ks < 2; ++ks)
      boff[ni][ks] =
          (wc * 64 + ni * 16 + l15) * 64 + (((ks * 4 + quad) ^ l7) * 8);

  // prologue: stage K-tile 0 into buffer 0
#pragma unroll
  for (int ri = 0; ri < 4; ++ri)
    gload_lds16(gaw + (size_t)(ri * 64) * 1024, daw + ri * 4096);
#pragma unroll
  for (int ri = 0; ri < 2; ++ri)
    gload_lds16(gbw + (size_t)(ri * 64) * 1024, dbw + ri * 4096);

  for (int kt = 0; kt < 16; ++kt) {
    const int buf = kt & 1;
    __syncthreads();  // own kt-loads drained; all reads of buf^1 done
    if (kt + 1 < 16) {
      const bf16* ga = gaw + (kt + 1) * 64;
      const bf16* gb = gbw + (kt + 1) * 64;
      bf16* da = daw + (buf ^ 1) * 16384;
      bf16* db = dbw + (buf ^ 1) * 8192;
#pragma unroll
      for (int ri = 0; ri < 4; ++ri)
        gload_lds16(ga + (size_t)(ri * 64) * 1024, da + ri * 4096);
#pragma unroll
      for (int ri = 0; ri < 2; ++ri)
        gload_lds16(gb + (size_t)(ri * 64) * 1024, db + ri * 4096);
    }
    const bf16* a_ = As + buf * 16384;
    const bf16* b_ = Bs + buf * 8192;
#pragma unroll
    for (int ks = 0; ks < 2; ++ks) {
      bf16x8 av[4], bv[4];
#pragma unroll
      for (int i = 0; i < 4; ++i)
        av[i] = *(const bf16x8*)(a_ + aoff[i][ks]);
#pragma unroll
      for (int i = 0; i < 4; ++i)
        bv[i] = *(const bf16x8*)(b_ + boff[i][ks]);
#pragma unroll
      for (int mi = 0; mi < 4; ++mi)
#pragma unroll
        for (int ni = 0; ni < 4; ++ni)
          acc[mi][ni] = __builtin_amdgcn_mfma_f32_16x16x32_bf16(
              av[mi], bv[ni], acc[mi][ni], 0, 0, 0);
    }
  }
  __syncthreads();  // epilogue reuses the mainloop LDS
}

// QKV projection: Q (pre-scaled), K, V all stored natural [B,S,H,64]
// (= [8192][1024] row-major). grid (24, 32): 256-row x 128-col tiles.
__global__ __launch_bounds__(512, 2) void k_gemm_qkv(
    const bf16* __restrict__ A, const bf16* __restrict__ BT,
    const float* __restrict__ bq, const float* __restrict__ bk,
    const float* __restrict__ bv, bf16* __restrict__ Q, bf16* __restrict__ K,
    bf16* __restrict__ V) {
  __shared__ alignas(16) char smem[98304];
  bf16* As = (bf16*)smem;            // 2 x 16384 elems
  bf16* Bs = (bf16*)(smem + 65536);  // 2 x 8192 elems
  f32x4 acc[4][4] = {};
  const int bm = blockIdx.y, bn = blockIdx.x;
  gemm256_mainloop(A, BT, bm, bn, As, Bs, acc);
  const int tid = threadIdx.x;
  const int w = tid >> 6, lane = tid & 63, quad = lane >> 4, l15 = lane & 15;
  const int wr = w >> 1, wc = w & 1;
  bf16* sEw = (bf16*)smem + w * 4608;  // per-wave [64][72]
  const int colbase = bn * 128 + wc * 64;  // multiple of 64 -> wave-uniform
  const int which = colbase >> 10;
  const int nnbase = colbase & 1023;
  const float* bias = which == 0 ? bq : which == 1 ? bk : bv;
  bf16* dst = which == 0 ? Q : which == 1 ? K : V;
  const float scl = which == 0 ? QSCALE : 1.f;
  const int rowbase = bm * 256 + wr * 64;
#pragma unroll
  for (int ni = 0; ni < 4; ++ni) {
    float bb = bias[nnbase + ni * 16 + l15];
#pragma unroll
    for (int mi = 0; mi < 4; ++mi)
#pragma unroll
      for (int r = 0; r < 4; ++r)
        sEw[(mi * 16 + quad * 4 + r) * 72 + ni * 16 + l15] =
            (__bf16)((acc[mi][ni][r] + bb) * scl);
  }
  // per-wave buffer: in-wave LDS ordering suffices, no barrier
  const int l8 = lane >> 3, g8 = (lane & 7) * 8;
#pragma unroll
  for (int i = 0; i < 8; ++i) {
    int row = i * 8 + l8;
    bf16x8 vv = *(const bf16x8*)(sEw + row * 72 + g8);
    *(bf16x8*)(dst + (size_t)(rowbase + row) * 1024 + nnbase + g8) = vv;
  }
}

// out projection: A=attn_out bf16 [8192][1024], BT=woT -> BF16 Yb (LN input).
// grid (8, 32): 256-row x 128-col tiles; qkv-style bf16 [64][72] epilogue.
// bf16-Y halves the Y write + LN read traffic; R7/R9 verified absmax
// unchanged (0.03125) with this exact rounding point.
__global__ __launch_bounds__(512, 2) void k_gemm_out(
    const bf16* __restrict__ A, const bf16* __restrict__ BT,
    const float* __restrict__ bo, bf16* __restrict__ Yb) {
  __shared__ alignas(16) char smem[98304];
  bf16* As = (bf16*)smem;
  bf16* Bs = (bf16*)(smem + 65536);
  f32x4 acc[4][4] = {};
  const int bm = blockIdx.y, bn = blockIdx.x;
  gemm256_mainloop(A, BT, bm, bn, As, Bs, acc);
  const int tid = threadIdx.x;
  const int w = tid >> 6, lane = tid & 63, quad = lane >> 4, l15 = lane & 15;
  const int wr = w >> 1, wc = w & 1;
  bf16* sEw = (bf16*)smem + w * 4608;  // per-wave [64][72]
  const int colbase = bn * 128 + wc * 64;
  const int rowbase = bm * 256 + wr * 64;
#pragma unroll
  for (int ni = 0; ni < 4; ++ni) {
    float bb = bo[colbase + ni * 16 + l15];
#pragma unroll
    for (int mi = 0; mi < 4; ++mi)
#pragma unroll
      for (int r = 0; r < 4; ++r)
        sEw[(mi * 16 + quad * 4 + r) * 72 + ni * 16 + l15] =
            (__bf16)(acc[mi][ni][r] + bb);
  }
  // per-wave buffer; in-wave ordering (ds in-order) makes this safe
  const int l8 = lane >> 3, g8 = (lane & 7) * 8;
#pragma unroll
  for (int i = 0; i < 8; ++i) {
    int row = i * 8 + l8;
    bf16x8 vv = *(const bf16x8*)(sEw + row * 72 + g8);
    *(bf16x8*)(Yb + (size_t)(rowbase + row) * 1024 + colbase + g8) = vv;
  }
}

// ---------------- flash attention v7 (proven 90.2 us) ----------------
// 1024 blocks, 4 waves x 32 q, 64-key chunks double-buffered, per-wave P tile
// [32 q][32 k] bf16 with row-parity-decorrelated granule swizzle
// sw = (l15>>1)&3. LDS 40960 B -> 4 blocks/CU, 16 waves/CU.
__global__ __launch_bounds__(256, 4) void k_attn(const bf16* __restrict__ Qg,
                                                 const bf16* __restrict__ Kg,
                                                 const bf16* __restrict__ VtG,
                                                 bf16* __restrict__ O) {
  __shared__ alignas(16) char smem[40960];
  bf16* sK = (bf16*)smem;              // 2 x 4096 elems
  bf16* sVt = (bf16*)(smem + 16384);   // 2 x 4096 elems
  const int tid = threadIdx.x;
  const int w = tid >> 6, lane = tid & 63, quad = lane >> 4, l15 = lane & 15;
  const int l7 = l15 & 7, l8 = lane >> 3;
  const int sw = (l15 >> 1) & 3;  // row-parity-decorrelated granule swizzle
  const int bh = blockIdx.x & 63;   // XCD-friendly: bh mod 8 fixed per bh
  const int qt = blockIdx.x >> 6;   // 0..15
  const int b = bh >> 4, h = bh & 15;
  const bf16* Qh = Qg + (size_t)b * NS * ND + h * HD;
  const bf16* Kh = Kg + (size_t)b * NS * ND + h * HD;
  const bf16* Vh = VtG + (size_t)bh * HD * NS;  // [64][2048]
  bf16* Pw = (bf16*)(smem + 32768) + w * 1024;  // per-wave [32][32] swizzled

  const int q0 = qt * 128 + w * 32;
  // Q B-fragments (pre-scaled at QKV epilogue), registers for whole kernel
  bf16x8 qb[2][2];
#pragma unroll
  for (int ni = 0; ni < 2; ++ni)
#pragma unroll
    for (int ks = 0; ks < 2; ++ks)
      qb[ni][ks] = *(const bf16x8*)(Qh + (size_t)(q0 + ni * 16 + l15) * ND +
                                    ks * 32 + quad * 8);

  // staging addresses (XOR-granule swizzle g^=row&7, lane-linear LDS dest)
  const int gsw = ((lane & 7) ^ l8) * 8;
  const bf16* gk = Kh + (size_t)(w * 8 + l8) * ND + gsw;
  const bf16* gv = Vh + (size_t)(w * 8 + l8) * NS + gsw;
  bf16* dk = sK + w * 512;
  bf16* dv = sVt + w * 512;

  f32x4 o_acc[4][2] = {};  // O^T: row d=mi*16+quad*4+r, col q=ni*16+l15
  float l_run[2] = {0.f, 0.f};  // lane-local partial denominators

  // chunk-invariant swizzled fragment offsets
  int offA[4][2];
#pragma unroll
  for (int mi = 0; mi < 4; ++mi)
#pragma unroll
    for (int ks = 0; ks < 2; ++ks)
      offA[mi][ks] = (mi * 16 + l15) * 64 + (((ks * 4 + quad) ^ l7) * 8);
  // P tile [32 q][32 k] bf16, 64 B rows, 4 granules of 16 B, XOR sw
  int offP[2], wbase[2], wg[2];
#pragma unroll
  for (int ni = 0; ni < 2; ++ni) {
    offP[ni] = (ni * 16 + l15) * 32 + ((quad ^ sw) * 8);
    wbase[ni] = (ni * 16 + l15) * 32 + (quad & 1) * 4;
  }
#pragma unroll
  for (int m2 = 0; m2 < 2; ++m2)
    wg[m2] = (((m2 * 2 + (quad >> 1)) ^ sw) * 8);

  // prologue: stage chunk 0 into buffer 0
  gload_lds16(gk, dk);
  gload_lds16(gk + 32 * ND, dk + 2048);
  gload_lds16(gv, dv);
  gload_lds16(gv + 32 * NS, dv + 2048);

  for (int it = 0; it < NS / 64; ++it) {
    const int buf = (it & 1) * 4096;
    __syncthreads();  // drains own chunk-it loads; all buf^1 reads done
    if (it + 1 < NS / 64) {
      const int nbuf = 4096 - buf;
      const bf16* gk1 = gk + (size_t)(it + 1) * 64 * ND;
      const bf16* gv1 = gv + (it + 1) * 64;
      gload_lds16(gk1, dk + nbuf);
      gload_lds16(gk1 + 32 * ND, dk + nbuf + 2048);
      gload_lds16(gv1, dv + nbuf);
      gload_lds16(gv1 + 32 * NS, dv + nbuf + 2048);
    }

#pragma unroll
    for (int hf = 0; hf < 2; ++hf) {  // 32-key half: keys hf*32..hf*32+31
      // S^T = K Q^T for mi = 2*hf + m2; exp2 + P-write immediately
#pragma unroll
      for (int m2 = 0; m2 < 2; ++m2) {
        const int mi = 2 * hf + m2;
        f32x4 s[2] = {};
#pragma unroll
        for (int ks = 0; ks < 2; ++ks) {
          bf16x8 ak = *(const bf16x8*)(sK + buf + offA[mi][ks]);
#pragma unroll
          for (int ni = 0; ni < 2; ++ni)
            s[ni] = __builtin_amdgcn_mfma_f32_16x16x32_bf16(ak, qb[ni][ks],
                                                            s[ni], 0, 0, 0);
        }
#pragma unroll
        for (int ni = 0; ni < 2; ++ni) {
#pragma unroll
          for (int r = 0; r < 4; ++r) {
            s[ni][r] = fast_exp2(s[ni][r]);
            l_run[ni] += s[ni][r];
          }
          bf16x4 p = {(__bf16)s[ni][0], (__bf16)s[ni][1], (__bf16)s[ni][2],
                      (__bf16)s[ni][3]};
          *(bf16x4*)(Pw + wbase[ni] + wg[m2]) = p;
        }
      }

      // O^T += V^T P^T for this 32-key half (ks = hf); per-wave P, no barrier
      bf16x8 pb[2];
#pragma unroll
      for (int ni = 0; ni < 2; ++ni)
        pb[ni] = *(const bf16x8*)(Pw + offP[ni]);
#pragma unroll
      for (int mi = 0; mi < 4; ++mi) {
        bf16x8 av = *(const bf16x8*)(sVt + buf + offA[mi][hf]);
#pragma unroll
        for (int ni = 0; ni < 2; ++ni)
          o_acc[mi][ni] = __builtin_amdgcn_mfma_f32_16x16x32_bf16(
              av, pb[ni], o_acc[mi][ni], 0, 0, 0);
      }
    }
  }

  // epilogue: finish denominator reduction, write attn_out [B,S,H*64] bf16
#pragma unroll
  for (int ni = 0; ni < 2; ++ni) {
    float l = l_run[ni];
    l += __shfl_xor(l, 16, 64);
    l += __shfl_xor(l, 32, 64);
    float inv = 1.f / l;
    int q = q0 + ni * 16 + l15;
    size_t orow = ((size_t)b * NS + q) * 1024 + h * 64;
#pragma unroll
    for (int mi = 0; mi < 4; ++mi) {
      bf16x4 ov = {
          (__bf16)(o_acc[mi][ni][0] * inv), (__bf16)(o_acc[mi][ni][1] * inv),
          (__bf16)(o_acc[mi][ni][2] * inv), (__bf16)(o_acc[mi][ni][3] * inv)};
      *(bf16x4*)(O + orow + mi * 16 + quad * 4) = ov;
    }
  }
}

// ------------- LayerNorm: bf16 Yb in -> fp32 out (saves 32MB traffic) ------
__global__ __launch_bounds__(256) void k_ln(const bf16* __restrict__ Yb,
                                            const float* __restrict__ g,
                                            const float* __restrict__ bta,
                                            float* __restrict__ out) {
  int row = blockIdx.x, tid = threadIdx.x;
  bf16x4 vb = *(const bf16x4*)(Yb + (size_t)row * 1024 + tid * 4);
  float4 v = {(float)vb[0], (float)vb[1], (float)vb[2], (float)vb[3]};
  float sm = v.x + v.y + v.z + v.w;
  float sq = v.x * v.x + v.y * v.y + v.z * v.z + v.w * v.w;
#pragma unroll
  for (int off = 1; off < 64; off <<= 1) {
    sm += __shfl_xor(sm, off, 64);
    sq += __shfl_xor(sq, off, 64);
  }
  __shared__ float red[8];
  int w = tid >> 6, lane = tid & 63;
  if (lane == 0) {
    red[w] = sm;
    red[4 + w] = sq;
  }
  __syncthreads();
  sm = red[0] + red[1] + red[2] + red[3];
  sq = red[4] + red[5] + red[6] + red[7];
  float mu = sm * (1.f / 1024.f);
  float var = sq * (1.f / 1024.f) - mu * mu;
  float rstd = rsqrtf(var + 1e-12f);
  float4 g4 = ((const float4*)g)[tid];
  float4 b4 = ((const float4*)bta)[tid];
  float4 o;
  o.x = (v.x - mu) * rstd * g4.x + b4.x;
  o.y = (v.y - mu) * rstd * g4.y + b4.y;
  o.z = (v.z - mu) * rstd * g4.z + b4.z;
  o.w = (v.w - mu) * rstd * g4.w + b4.w;
  ((float4*)(out + (size_t)row * 1024))[tid] = o;
}

extern "C" void kernel_launch(void* const* d_in, const int* in_sizes, int n_in,
                              void* d_out, int out_size, void* d_ws,
                              size_t ws_size, hipStream_t stream) {
  const float* x = (const float*)d_in[0];
  const float* wq = (const float*)d_in[1];
  const float* bq = (const float*)d_in[2];
  const float* wk = (const float*)d_in[3];
  const float* bk = (const float*)d_in[4];
  const float* wv = (const float*)d_in[5];
  const float* bv = (const float*)d_in[6];
  const float* wo = (const float*)d_in[7];
  const float* bo = (const float*)d_in[8];
  const float* ln_g = (const float*)d_in[9];
  const float* ln_b = (const float*)d_in[10];
  float* out = (float*)d_out;

  char* ws = (char*)d_ws;
  bf16* xb = (bf16*)ws;          ws += 16777216;   // [8192][1024]
  bf16* wqkvT = (bf16*)ws;       ws += 6291456;    // [3072][1024]
  bf16* woT = (bf16*)ws;         ws += 2097152;    // [1024][1024]
  bf16* Qh = (bf16*)ws;          ws += 16777216;   // [B,S,H,64] (pre-scaled)
  bf16* Kh = (bf16*)ws;          ws += 16777216;   // [B,S,H,64]
  bf16* Vh = (bf16*)ws;          ws += 16777216;   // [B,S,H,64]
  bf16* Vt = (bf16*)ws;          ws += 16777216;   // [B,H,64,S] (transposed)
  bf16* AOb = (bf16*)ws;         ws += 16777216;   // [8192][1024]
  bf16* Yb = (bf16*)ws;          ws += 16777216;   // [8192][1024] (LN input)

  k_prep<<<12288, 256, 0, stream>>>(x, xb, wq, wk, wv, wo, wqkvT, woT);

  k_gemm_qkv<<<dim3(24, 32), 512, 0, stream>>>(xb, wqkvT, bq, bk, bv, Qh, Kh,
                                               Vh);
  k_vT<<<NB * NH * 32, 256, 0, stream>>>(Vh, Vt);
  k_attn<<<NB * NH * (NS / 128), 256, 0, stream>>>(Qh, Kh, Vt, AOb);
  k_gemm_out<<<dim3(8, 32), 512, 0, stream>>>(AOb, woT, bo, Yb);
  k_ln<<<8192, 256, 0, stream>>>(Yb, ln_g, ln_b, out);
}